// Round 1
// baseline (443.714 us; speedup 1.0000x reference)
//
#include <hip/hip_runtime.h>

// GODE on MI355X. bf16 MFMA, fp32 accum, h TRANSPOSED: hT[(b*128+d)][n].
// R5 algebra: (adj@h)@W_half == adj@(h@W_half)  -> big GEMM per step is
// [64 j x 2048 n2, K=2048] per batch. hW (h@W_half, transposed hWT[(b*64+j)][n])
// is produced in the PREVIOUS kernel's epilogue.
// R6 (this round): (a) quad-major LDS panels [g16][kq][row][8] so the linear
// global_load_lds lane order == fragment-read order -> ds_read_b128 is 2-way
// (free) instead of 8-way bank conflict; (b) double-buffered 2-phase K-loops
// (stage t+1 issued before compute of t, ONE barrier/iter) so global->LDS
// latency hides under ds_read+MFMA. fused_step2: BK=64 x 32 iters, dbuf fits
// the same 48KB -> 2 blocks/CU kept.

typedef unsigned short u16;
typedef unsigned int   u32;
typedef unsigned long long u64;
typedef __attribute__((ext_vector_type(8))) short bf8;  // 8 raw bf16 (4 VGPRs)
typedef __attribute__((ext_vector_type(4))) float f4;

#define AS1 __attribute__((address_space(1)))
#define AS3 __attribute__((address_space(3)))

__device__ __forceinline__ void gl_lds16(const void* g, void* l) {
  __builtin_amdgcn_global_load_lds((const AS1 u32*)g, (AS3 u32*)l, 16, 0, 0);
}
__device__ __forceinline__ float bf2f(u16 v) {
  u32 u = ((u32)v) << 16; return __builtin_bit_cast(float, u);
}
__device__ __forceinline__ u16 f2bf(float f) {  // RNE
  u32 u = __builtin_bit_cast(u32, f);
  return (u16)((u + 0x7fffu + ((u >> 16) & 1u)) >> 16);
}
__device__ __forceinline__ float ldf(const void* p, size_t i, u32 isf32) {
  return isf32 ? ((const float*)p)[i] : bf2f(((const u16*)p)[i]);
}

// ---- quad-major staging ----
// Tile of R rows x 32 k is stored as [R/16 groups][4 kquads][16 rows][8 bf16];
// one group = 512 u16 = 1KB. global_load_lds writes lane*16B, so lane
// (row=lane&15, kq=lane>>4) lands element block (g, kq, row) exactly.
// Fragment read for lane (col,quad): lds[g*512 + quad*128 + col*8] -> the 16
// lanes of a quarter-wave read 16 CONSECUTIVE 16B units: conflict-free.
__device__ __forceinline__ void stage64x32q(const u16* g, int stride, u16* lds,
                                            int wave, int lane) {
  gl_lds16(g + (size_t)(wave * 16 + (lane & 15)) * stride + (lane >> 4) * 8,
           lds + wave * 512);
}
__device__ __forceinline__ void stage128x32q(const u16* g, int stride, u16* lds,
                                             int wave, int lane) {
  int r = lane & 15, qk = (lane >> 4) * 8;
  gl_lds16(g + (size_t)(wave * 16 + r) * stride + qk, lds + wave * 512);
  gl_lds16(g + (size_t)((wave + 4) * 16 + r) * stride + qk, lds + (wave + 4) * 512);
}

// ---------------- dtype detection ----------------
__global__ void detect_dtype(const u16* __restrict__ x_raw, u32* __restrict__ flag) {
  __shared__ int s;
  int tid = threadIdx.x;
  if (tid == 0) s = 0;
  __syncthreads();
  int huge = 0;
#pragma unroll
  for (int j = 0; j < 16; ++j) {
    u16 v = x_raw[tid * 16 + j];
    u32 e = (v >> 7) & 0xFF;
    if (e >= 0xC0) huge = 1;          // |v| >= 2^64: impossible for N(0,1) bf16
  }
  if (huge) atomicOr(&s, 1);
  __syncthreads();
  if (tid == 0) flag[0] = (u32)s;     // 1 = f32 inputs, 0 = bf16 inputs
}

// ---------------- generic convert to bf16 (adj) ----------------
__global__ void cvt_bf16(const void* __restrict__ in, u16* __restrict__ out,
                         long in_off, int n, const u32* __restrict__ flag) {
  u32 isf32 = flag[0];
  int gid = blockIdx.x * 256 + threadIdx.x;
  long i = in_off + (long)gid * 4;
  if (gid * 4 >= n) return;
  u16 o0, o1, o2, o3;
  if (isf32) {
    f4 v = *(const f4*)&((const float*)in)[i];
    o0 = f2bf(v[0]); o1 = f2bf(v[1]); o2 = f2bf(v[2]); o3 = f2bf(v[3]);
  } else {
    u64 v = *(const u64*)&((const u16*)in)[i];
    o0 = (u16)v; o1 = (u16)(v >> 16); o2 = (u16)(v >> 32); o3 = (u16)(v >> 48);
  }
  u64 pk = (u64)o0 | ((u64)o1 << 16) | ((u64)o2 << 32) | ((u64)o3 << 48);
  *(u64*)&out[(size_t)gid * 4] = pk;
}

// ---------------- weight pre-transpose ----------------
// WaT[256][256]=Wa^T, WbT[128][256]=Wb^T, W1T[64][128]=W1[:, :64]^T, W2T[64][128]=W2[:, 64:]^T
__global__ void prep_weights(const void* __restrict__ Wa, const void* __restrict__ Wb,
                             const void* __restrict__ W1, const void* __restrict__ W2,
                             u16* __restrict__ WaT, u16* __restrict__ WbT,
                             u16* __restrict__ W1T, u16* __restrict__ W2T,
                             const u32* __restrict__ flag) {
  u32 isf32 = flag[0];
  int i = blockIdx.x * 256 + threadIdx.x;
  if (i < 65536) {
    int o = i >> 8, k = i & 255; WaT[o * 256 + k] = f2bf(ldf(Wa, (size_t)k * 256 + o, isf32));
  } else if (i < 98304) {
    int j = i - 65536; int o = j >> 8, k = j & 255;
    WbT[o * 256 + k] = f2bf(ldf(Wb, (size_t)k * 128 + o, isf32));
  } else if (i < 106496) {
    int j = i - 98304; int jj = j >> 7, k = j & 127;
    W1T[jj * 128 + k] = f2bf(ldf(W1, (size_t)k * 128 + jj, isf32));
  } else {
    int j = i - 106496; int jj = j >> 7, k = j & 127;
    W2T[jj * 128 + k] = f2bf(ldf(W2, (size_t)k * 128 + 64 + jj, isf32));
  }
}

// ---------------- fused MLP + first hW ----------------
// hT = tanh(relu([x,hz]@Wa+ba)@Wb+bb)  (transposed store), and
// hW1T[(b*64+j)][n] = sum_d W1T[j][d] * h0[n-row][d]  (epilogue in-LDS GEMM).
// Pipelined: both phase K-loops double-buffered, 1 barrier/iter.
__global__ __launch_bounds__(256, 2) void mlp_fused(const void* __restrict__ x,
                                                    const void* __restrict__ hz,
                                                    const u16* __restrict__ WaT,
                                                    const void* __restrict__ ba,
                                                    const u16* __restrict__ WbT,
                                                    const void* __restrict__ bb,
                                                    const u16* __restrict__ W1T,
                                                    u16* __restrict__ hT,
                                                    u16* __restrict__ hW,
                                                    const u32* __restrict__ flag) {
  __shared__ __align__(16) u16 Z[64 * 264];     // 33.8 KB
  // pool: [lA dbuf 2x2048][lB dbuf 2x8192] = 20480 u16 = 40 KB. Phase2 reuses
  // [4096,12288) as lB2 dbuf (2x4096). hN[64][136]=8704 u16 overlays from 0.
  __shared__ __align__(16) u16 pool[20480];
  u16* hN = pool;
  u32 isf32 = flag[0];
  int tid = threadIdx.x, lane = tid & 63, wave = tid >> 6;
  int col = lane & 15, quad = lane >> 4;
  int r0 = blockIdx.x * 64;
  int b = r0 >> 11;

  struct A2 { uint4 a, b; };
  auto loadA = [&](int kk) -> A2 {
    int k0 = kk * 32;
    const void* src = (kk < 4) ? x : hz;
    int csrc = (kk < 4) ? k0 : (k0 - 128);
    int row = tid >> 2, c0 = (tid & 3) * 8;
    size_t g = (size_t)(r0 + row) * 128 + csrc + c0;
    A2 v;
    if (isf32) {
      v.a = *(const uint4*)&((const float*)src)[g];
      v.b = *(const uint4*)&((const float*)src)[g + 4];
    } else {
      v.a = *(const uint4*)&((const u16*)src)[g];
    }
    return v;
  };
  auto writeA = [&](int buf, A2 v) {
    uint4 pk;
    if (isf32) {
      f4 v0 = __builtin_bit_cast(f4, v.a), v1 = __builtin_bit_cast(f4, v.b);
      pk.x = (u32)f2bf(v0[0]) | ((u32)f2bf(v0[1]) << 16);
      pk.y = (u32)f2bf(v0[2]) | ((u32)f2bf(v0[3]) << 16);
      pk.z = (u32)f2bf(v1[0]) | ((u32)f2bf(v1[1]) << 16);
      pk.w = (u32)f2bf(v1[2]) | ((u32)f2bf(v1[3]) << 16);
    } else {
      pk = v.a;
    }
    int row = tid >> 2;
    *(uint4*)&pool[buf * 2048 + (row >> 4) * 512 + (tid & 3) * 128 + (row & 15) * 8] = pk;
  };
  auto stageB1 = [&](int buf, int kk) {
    int k0 = kk * 32;
    u16* lb = pool + 4096 + buf * 8192;
    stage128x32q(WaT + k0, 256, lb, wave, lane);
    stage128x32q(WaT + (size_t)128 * 256 + k0, 256, lb + 4096, wave, lane);
  };

  // phase 1: Z = relu(u @ Wa + ba), u = [x|hz], tile 64 x 256
  f4 acc[4][4] = {};
  {
    A2 v0 = loadA(0);
    stageB1(0, 0);
    writeA(0, v0);
  }
  __syncthreads();
  for (int kk = 0; kk < 8; ++kk) {
    int cur = kk & 1;
    A2 nx;
    if (kk < 7) { nx = loadA(kk + 1); stageB1(cur ^ 1, kk + 1); }
    const u16* la = pool + cur * 2048;
    const u16* lb = pool + 4096 + cur * 8192;
    bf8 af[4], bfr[4];
#pragma unroll
    for (int mi = 0; mi < 4; ++mi) af[mi] = *(const bf8*)&la[mi * 512 + quad * 128 + col * 8];
#pragma unroll
    for (int nj = 0; nj < 4; ++nj) bfr[nj] = *(const bf8*)&lb[(wave * 4 + nj) * 512 + quad * 128 + col * 8];
#pragma unroll
    for (int mi = 0; mi < 4; ++mi)
#pragma unroll
      for (int nj = 0; nj < 4; ++nj)
        acc[mi][nj] = __builtin_amdgcn_mfma_f32_16x16x32_bf16(af[mi], bfr[nj], acc[mi][nj], 0, 0, 0);
    if (kk < 7) writeA(cur ^ 1, nx);
    __syncthreads();
  }

  // stage first WbT tile while writing Z
  auto stageB2 = [&](int buf, int kk) {
    stage128x32q(WbT + kk * 32, 256, pool + 4096 + buf * 4096, wave, lane);
  };
  stageB2(0, 0);
#pragma unroll
  for (int mi = 0; mi < 4; ++mi)
#pragma unroll
    for (int nj = 0; nj < 4; ++nj) {
      int o = wave * 64 + nj * 16 + col;
      float bav = ldf(ba, o, isf32);
      int rl = mi * 16 + quad * 4;
#pragma unroll
      for (int r = 0; r < 4; ++r)
        Z[(rl + r) * 264 + o] = f2bf(fmaxf(acc[mi][nj][r] + bav, 0.f));
    }
  __syncthreads();

  // phase 2: h0 = tanh(Z @ Wb + bb); A-frags from Z (stride 264: conflict-free)
  f4 acc2[4][2] = {};
  for (int kk = 0; kk < 8; ++kk) {
    int cur = kk & 1;
    if (kk < 7) stageB2(cur ^ 1, kk + 1);
    int k0 = kk * 32;
    const u16* lb = pool + 4096 + cur * 4096;
    bf8 az[4], bw[2];
#pragma unroll
    for (int mi = 0; mi < 4; ++mi) az[mi] = *(const bf8*)&Z[(mi * 16 + col) * 264 + k0 + quad * 8];
#pragma unroll
    for (int nj = 0; nj < 2; ++nj) bw[nj] = *(const bf8*)&lb[(wave * 2 + nj) * 512 + quad * 128 + col * 8];
#pragma unroll
    for (int mi = 0; mi < 4; ++mi)
#pragma unroll
      for (int nj = 0; nj < 2; ++nj)
        acc2[mi][nj] = __builtin_amdgcn_mfma_f32_16x16x32_bf16(az[mi], bw[nj], acc2[mi][nj], 0, 0, 0);
    __syncthreads();
  }

  // epilogue: tanh(+bb) -> global hT (transposed) AND hN[r][d] staging for hW1
#pragma unroll
  for (int mi = 0; mi < 4; ++mi)
#pragma unroll
    for (int nj = 0; nj < 2; ++nj) {
      int d = wave * 32 + nj * 16 + col;
      float bbv = ldf(bb, d, isf32);
      int rl = mi * 16 + quad * 4;
      int rabs = r0 + rl;
      int n = rabs & 2047;
      u16 p[4];
#pragma unroll
      for (int r = 0; r < 4; ++r) {
        p[r] = f2bf(tanhf(acc2[mi][nj][r] + bbv));
        hN[(rl + r) * 136 + d] = p[r];
      }
      u64 pk = (u64)p[0] | ((u64)p[1] << 16) | ((u64)p[2] << 32) | ((u64)p[3] << 48);
      *(u64*)&hT[(size_t)(b * 128 + d) * 2048 + n] = pk;
    }
  __syncthreads();

  // hW1: out[j][r] = sum_d W1T[j][d] * hN[r][d]; wave covers r in [wave*16, wave*16+16)
  f4 acc3[4] = {};
#pragma unroll
  for (int ks = 0; ks < 4; ++ks) {
    bf8 aw[4], bg;
#pragma unroll
    for (int mi = 0; mi < 4; ++mi)
      aw[mi] = *(const bf8*)&W1T[(size_t)(mi * 16 + col) * 128 + ks * 32 + quad * 8];
    bg = *(const bf8*)&hN[(wave * 16 + col) * 136 + ks * 32 + quad * 8];
#pragma unroll
    for (int mi = 0; mi < 4; ++mi)
      acc3[mi] = __builtin_amdgcn_mfma_f32_16x16x32_bf16(aw[mi], bg, acc3[mi], 0, 0, 0);
  }
#pragma unroll
  for (int mi = 0; mi < 4; ++mi) {
    int rloc = wave * 16 + col;
    int ng = (r0 & 2047) + rloc;
#pragma unroll
    for (int r = 0; r < 4; ++r) {
      int j = mi * 16 + quad * 4 + r;
      hW[(size_t)(b * 64 + j) * 2048 + ng] = f2bf(acc3[mi][r]);
    }
  }
}

// ---------------- fused diffusion step (v3: dbuf BK=64 pipeline, quad-major) ----
// Big GEMM: G[m=(b,j)][n2] = sum_n hWT[(b*64+j)][n] * adjb[n2][n]  (64x128 tile, K=2048)
// Update: nh = hin + DT*tanh(G)  (eps step: *= clip(eps,0,0.1)); write updated half +
// copy untouched half to hout. If WnT: stage hnew into gN[n][d] and produce next
// hWout[(b*64+j')][n] = sum_d WnT[j'][d] * gN[n][d]  (in-LDS pass-2).
__global__ __launch_bounds__(256, 2) void fused_step2(const u16* __restrict__ hin,
                                                      const u16* __restrict__ hWT,
                                                      const u16* __restrict__ adjb,
                                                      const u16* __restrict__ WnT,
                                                      const void* __restrict__ eps,
                                                      u16* __restrict__ hout,
                                                      u16* __restrict__ hWout,
                                                      int half, const u32* __restrict__ flag) {
  // [lA0 4096][lA1 4096][lB0 8192][lB1 8192] = 24576 u16 = 48 KB -> 2 blocks/CU
  __shared__ __align__(16) u16 smem[24576];
  u16* gN = smem;               // [128][136] = 17408 u16, overlays post K-loop
  u32 isf32 = flag[0];
  int tid = threadIdx.x, lane = tid & 63, wave = tid >> 6;
  int col = lane & 15, quad = lane >> 4;
  int b = blockIdx.y;
  int n0 = blockIdx.x * 128;

  const u16* Arow = hWT + (size_t)(b * 64) * 2048;
  const u16* Brow = adjb + (size_t)n0 * 2048;

  auto STAGE = [&](int buf, int t) {
    int k0 = t * 64;
    u16* la = smem + buf * 4096;
    u16* lb = smem + 8192 + buf * 8192;
#pragma unroll
    for (int p = 0; p < 2; ++p) {
      int kp = k0 + p * 32;
      stage64x32q(Arow + kp, 2048, la + p * 2048, wave, lane);
      stage128x32q(Brow + kp, 2048, lb + p * 4096, wave, lane);
    }
  };

  f4 acc[4][2] = {};
  STAGE(0, 0);
  __syncthreads();
#pragma unroll 2
  for (int kk = 0; kk < 32; ++kk) {
    int cur = kk & 1;
    if (kk < 31) STAGE(cur ^ 1, kk + 1);
    const u16* la = smem + cur * 4096;
    const u16* lb = smem + 8192 + cur * 8192;
#pragma unroll
    for (int p = 0; p < 2; ++p) {
      bf8 af[4], bfr[2];
#pragma unroll
      for (int mi = 0; mi < 4; ++mi)
        af[mi] = *(const bf8*)&la[p * 2048 + mi * 512 + quad * 128 + col * 8];
#pragma unroll
      for (int nj = 0; nj < 2; ++nj)
        bfr[nj] = *(const bf8*)&lb[p * 4096 + (wave * 2 + nj) * 512 + quad * 128 + col * 8];
#pragma unroll
      for (int mi = 0; mi < 4; ++mi)
#pragma unroll
        for (int nj = 0; nj < 2; ++nj)
          acc[mi][nj] = __builtin_amdgcn_mfma_f32_16x16x32_bf16(af[mi], bfr[nj], acc[mi][nj], 0, 0, 0);
    }
    __syncthreads();
  }

  bool has_eps = (eps != nullptr);
  bool mk_hw = (WnT != nullptr);
  int dBase = half * 64;
  // update + write updated half; stage nh into gN[n][dBase+j]
#pragma unroll
  for (int mi = 0; mi < 4; ++mi)
#pragma unroll
    for (int nj = 0; nj < 2; ++nj) {
      int j0 = mi * 16 + quad * 4;
      int nl = wave * 32 + nj * 16 + col;
      int n = n0 + nl;
      float ev[4];
      if (has_eps) {
        size_t eoff = ((size_t)b * 2048 + n) * 64 + j0;
        if (isf32) {
          f4 e = *(const f4*)&((const float*)eps)[eoff];
          ev[0] = e[0]; ev[1] = e[1]; ev[2] = e[2]; ev[3] = e[3];
        } else {
          u64 e = *(const u64*)&((const u16*)eps)[eoff];
          ev[0] = bf2f((u16)e); ev[1] = bf2f((u16)(e >> 16));
          ev[2] = bf2f((u16)(e >> 32)); ev[3] = bf2f((u16)(e >> 48));
        }
      }
      u16 pv[4];
#pragma unroll
      for (int r = 0; r < 4; ++r) {
        int j = j0 + r;
        size_t idx = (size_t)(b * 128 + dBase + j) * 2048 + n;
        float hold = bf2f(hin[idx]);
        float nh = hold + 0.01f * tanhf(acc[mi][nj][r]);
        if (has_eps) {
          float e = fminf(fmaxf(ev[r], 0.f), 0.1f);
          nh = e * nh;
        }
        pv[r] = f2bf(nh);
        hout[idx] = pv[r];
      }
      if (mk_hw) {
        u64 pk = (u64)pv[0] | ((u64)pv[1] << 16) | ((u64)pv[2] << 32) | ((u64)pv[3] << 48);
        *(u64*)&gN[nl * 136 + dBase + j0] = pk;
      }
    }

  // copy untouched half to hout; also scatter into gN[n][oh+row]
  {
    int oh = (1 - half) * 64;
    const u16* src = hin + (size_t)(b * 128 + oh) * 2048 + n0;
    u16* dst = hout + (size_t)(b * 128 + oh) * 2048 + n0;
#pragma unroll
    for (int i = 0; i < 4; ++i) {
      int idx = i * 256 + tid;
      int rr = idx >> 4;
      int cc = (idx & 15) * 8;
      uint4 v = *(const uint4*)&src[(size_t)rr * 2048 + cc];
      *(uint4*)&dst[(size_t)rr * 2048 + cc] = v;
      if (mk_hw) {
        u16 t[8];
        *(uint4*)t = v;
#pragma unroll
        for (int q = 0; q < 8; ++q) gN[(cc + q) * 136 + oh + rr] = t[q];
      }
    }
  }

  if (mk_hw) {
    __syncthreads();
    // next hW: out[j'][n] = sum_d WnT[j'][d] * gN[n][d]
    f4 acc2[4][2] = {};
#pragma unroll
    for (int ks = 0; ks < 4; ++ks) {
      bf8 aw[4], bg[2];
#pragma unroll
      for (int mi = 0; mi < 4; ++mi)
        aw[mi] = *(const bf8*)&WnT[(size_t)(mi * 16 + col) * 128 + ks * 32 + quad * 8];
#pragma unroll
      for (int nj = 0; nj < 2; ++nj)
        bg[nj] = *(const bf8*)&gN[(wave * 32 + nj * 16 + col) * 136 + ks * 32 + quad * 8];
#pragma unroll
      for (int mi = 0; mi < 4; ++mi)
#pragma unroll
        for (int nj = 0; nj < 2; ++nj)
          acc2[mi][nj] = __builtin_amdgcn_mfma_f32_16x16x32_bf16(aw[mi], bg[nj], acc2[mi][nj], 0, 0, 0);
    }
#pragma unroll
    for (int mi = 0; mi < 4; ++mi)
#pragma unroll
      for (int nj = 0; nj < 2; ++nj) {
        int jp0 = mi * 16 + quad * 4;
        int n = n0 + wave * 32 + nj * 16 + col;
#pragma unroll
        for (int r = 0; r < 4; ++r)
          hWout[(size_t)(b * 64 + jp0 + r) * 2048 + n] = f2bf(acc2[mi][nj][r]);
      }
  }
}

// ---------------- final un-transpose: out[b][n][d] = hT[(b*128+d)][n] ----------------
__global__ void untranspose(const u16* __restrict__ hT, void* __restrict__ out,
                            const u32* __restrict__ flag) {
  __shared__ __align__(16) u16 t[64][65];
  u32 isf32 = flag[0];
  int b = blockIdx.z, d0 = blockIdx.y * 64, n0 = blockIdx.x * 64;
  int tid = threadIdx.x;
#pragma unroll
  for (int i = 0; i < 16; ++i) {
    int idx = tid + i * 256;
    int r = idx >> 6, c = idx & 63;
    t[r][c] = hT[(size_t)(b * 128 + d0 + r) * 2048 + n0 + c];
  }
  __syncthreads();
#pragma unroll
  for (int i = 0; i < 16; ++i) {
    int idx = tid + i * 256;
    int r = idx >> 6, c = idx & 63;  // r = n-local, c = d-local
    size_t o = (size_t)(b * 2048 + n0 + r) * 128 + d0 + c;
    if (isf32) ((float*)out)[o] = bf2f(t[c][r]);
    else       ((u16*)out)[o] = t[c][r];
  }
}

extern "C" void kernel_launch(void* const* d_in, const int* in_sizes, int n_in,
                              void* d_out, int out_size, void* d_ws, size_t ws_size,
                              hipStream_t stream) {
  const void* x   = d_in[0];
  const void* hz  = d_in[1];
  const void* adj = d_in[2];
  const void* W1  = d_in[3];
  const void* W2  = d_in[4];
  const void* Wa  = d_in[5];
  const void* ba  = d_in[6];
  const void* Wb  = d_in[7];
  const void* bb  = d_in[8];
  const void* eps = d_in[9];

  // workspace layout (44.3 MB):
  //   hA   @  0M   16.78 MB  transposed h ping buffer (bf16 [4096][2048])
  //   adjb @ 17M    8.39 MB  adj bf16 [2048][2048]
  //   hWa  @ 26M    8.39 MB  hW ping (bf16 [2048][2048])
  //   hWb  @ 35M    8.39 MB  hW pong
  //   weights @ 44M (229 KB), flag after
  // hB (pong h) = d_out scratch; untranspose fully rewrites d_out at the end.
  char* ws = (char*)d_ws;
  u16* hA   = (u16*)(ws);
  u16* adjb = (u16*)(ws + (17ull << 20));
  u16* hWa  = (u16*)(ws + (26ull << 20));
  u16* hWb  = (u16*)(ws + (35ull << 20));
  u16* WaT  = (u16*)(ws + (44ull << 20));
  u16* WbT  = WaT + 256 * 256;
  u16* W1T  = WbT + 128 * 256;
  u16* W2T  = W1T + 64 * 128;
  u32* flag = (u32*)(W2T + 64 * 128);
  u16* hB   = (u16*)d_out;

  detect_dtype<<<dim3(1), dim3(256), 0, stream>>>((const u16*)x, flag);
  prep_weights<<<dim3(448), dim3(256), 0, stream>>>(Wa, Wb, W1, W2, WaT, WbT, W1T, W2T, flag);
  cvt_bf16<<<dim3(4096), dim3(256), 0, stream>>>(adj, adjb, 0, 4194304, flag);
  mlp_fused<<<dim3(1024), dim3(256), 0, stream>>>(x, hz, WaT, ba, WbT, bb, W1T, hA, hWa, flag);
  // step 1 (half=0, consumes hWa=h0@W1h, produces hWb=h1@W2h)
  fused_step2<<<dim3(16, 32), dim3(256), 0, stream>>>(hA, hWa, adjb, W2T, nullptr, hB, hWb, 0, flag);
  // step 2 (half=1, eps; consumes hWb, produces hWa=h2@W1h)
  fused_step2<<<dim3(16, 32), dim3(256), 0, stream>>>(hB, hWb, adjb, W1T, eps, hA, hWa, 1, flag);
  // step 3 (half=0; consumes hWa, produces hWb=h3@W2h)
  fused_step2<<<dim3(16, 32), dim3(256), 0, stream>>>(hA, hWa, adjb, W2T, nullptr, hB, hWb, 0, flag);
  // step 4 (half=1, eps; consumes hWb, no next hW)
  fused_step2<<<dim3(16, 32), dim3(256), 0, stream>>>(hB, hWb, adjb, nullptr, eps, hA, nullptr, 1, flag);
  untranspose<<<dim3(32, 2, 32), dim3(256), 0, stream>>>(hA, d_out, flag);
}

// Round 2
// 432.543 us; speedup vs baseline: 1.0258x; 1.0258x over previous
//
#include <hip/hip_runtime.h>

// GODE on MI355X. bf16 MFMA, fp32 accum, h TRANSPOSED: hT[(b*128+d)][n].
// R5 algebra: (adj@h)@W_half == adj@(h@W_half)  -> big GEMM per step is
// [64 j x 2048 n2, K=2048] per batch. hW (h@W_half, transposed hWT[(b*64+j)][n])
// is produced in the PREVIOUS kernel's epilogue.
// R7: counted-vmcnt pipeline (T3+T4): raw s_barrier + asm s_waitcnt vmcnt(N),
// N = ops-per-tile x tiles-in-flight, NEVER 0 in steady state (R6's
// __syncthreads drained vmcnt(0) every iter -> regression). Triple-buffered
// LDS so stage(t+2) issued after barrier(t) never aliases the buffer being
// read. Quad-major panels ([g16][kq][16r][8]) keep ds_read_b128 conflict-free.
// mlp_fused: A-tile preloaded to LDS once (conflict-free linear writes);
// hot loops stage only B.

typedef unsigned short u16;
typedef unsigned int   u32;
typedef unsigned long long u64;
typedef __attribute__((ext_vector_type(8))) short bf8;  // 8 raw bf16 (4 VGPRs)
typedef __attribute__((ext_vector_type(4))) float f4;

#define AS1 __attribute__((address_space(1)))
#define AS3 __attribute__((address_space(3)))
#define WAITVM(N) asm volatile("s_waitcnt vmcnt(" #N ")" ::: "memory")
#define BARS __builtin_amdgcn_s_barrier()

__device__ __forceinline__ void gl_lds16(const void* g, void* l) {
  __builtin_amdgcn_global_load_lds((const AS1 u32*)g, (AS3 u32*)l, 16, 0, 0);
}
__device__ __forceinline__ float bf2f(u16 v) {
  u32 u = ((u32)v) << 16; return __builtin_bit_cast(float, u);
}
__device__ __forceinline__ u16 f2bf(float f) {  // RNE
  u32 u = __builtin_bit_cast(u32, f);
  return (u16)((u + 0x7fffu + ((u >> 16) & 1u)) >> 16);
}
__device__ __forceinline__ float ldf(const void* p, size_t i, u32 isf32) {
  return isf32 ? ((const float*)p)[i] : bf2f(((const u16*)p)[i]);
}

// ---- quad-major staging ----
// R rows x 32 k stored as [R/16 groups][4 kquads][16 rows][8 bf16]; group=1KB.
// global_load_lds writes lane*16B; lane (row=lane&15, kq=lane>>4) lands block
// (g,kq,row). Fragment read lane(col,quad): g*512 + quad*128 + col*8 -> the 16
// lanes of a quarter-wave read 16 CONSECUTIVE 16B units: conflict-free.
__device__ __forceinline__ void stage64x32q(const u16* g, int stride, u16* lds,
                                            int wave, int lane) {
  gl_lds16(g + (size_t)(wave * 16 + (lane & 15)) * stride + (lane >> 4) * 8,
           lds + wave * 512);
}
__device__ __forceinline__ void stage128x32q(const u16* g, int stride, u16* lds,
                                             int wave, int lane) {
  int r = lane & 15, qk = (lane >> 4) * 8;
  gl_lds16(g + (size_t)(wave * 16 + r) * stride + qk, lds + wave * 512);
  gl_lds16(g + (size_t)((wave + 4) * 16 + r) * stride + qk, lds + (wave + 4) * 512);
}

// ---------------- dtype detection ----------------
__global__ void detect_dtype(const u16* __restrict__ x_raw, u32* __restrict__ flag) {
  __shared__ int s;
  int tid = threadIdx.x;
  if (tid == 0) s = 0;
  __syncthreads();
  int huge = 0;
#pragma unroll
  for (int j = 0; j < 16; ++j) {
    u16 v = x_raw[tid * 16 + j];
    u32 e = (v >> 7) & 0xFF;
    if (e >= 0xC0) huge = 1;          // |v| >= 2^64: impossible for N(0,1) bf16
  }
  if (huge) atomicOr(&s, 1);
  __syncthreads();
  if (tid == 0) flag[0] = (u32)s;     // 1 = f32 inputs, 0 = bf16 inputs
}

// ---------------- generic convert to bf16 (adj) ----------------
__global__ void cvt_bf16(const void* __restrict__ in, u16* __restrict__ out,
                         long in_off, int n, const u32* __restrict__ flag) {
  u32 isf32 = flag[0];
  int gid = blockIdx.x * 256 + threadIdx.x;
  long i = in_off + (long)gid * 4;
  if (gid * 4 >= n) return;
  u16 o0, o1, o2, o3;
  if (isf32) {
    f4 v = *(const f4*)&((const float*)in)[i];
    o0 = f2bf(v[0]); o1 = f2bf(v[1]); o2 = f2bf(v[2]); o3 = f2bf(v[3]);
  } else {
    u64 v = *(const u64*)&((const u16*)in)[i];
    o0 = (u16)v; o1 = (u16)(v >> 16); o2 = (u16)(v >> 32); o3 = (u16)(v >> 48);
  }
  u64 pk = (u64)o0 | ((u64)o1 << 16) | ((u64)o2 << 32) | ((u64)o3 << 48);
  *(u64*)&out[(size_t)gid * 4] = pk;
}

// ---------------- weight pre-transpose ----------------
// WaT[256][256]=Wa^T, WbT[128][256]=Wb^T, W1T[64][128]=W1[:, :64]^T, W2T[64][128]=W2[:, 64:]^T
__global__ void prep_weights(const void* __restrict__ Wa, const void* __restrict__ Wb,
                             const void* __restrict__ W1, const void* __restrict__ W2,
                             u16* __restrict__ WaT, u16* __restrict__ WbT,
                             u16* __restrict__ W1T, u16* __restrict__ W2T,
                             const u32* __restrict__ flag) {
  u32 isf32 = flag[0];
  int i = blockIdx.x * 256 + threadIdx.x;
  if (i < 65536) {
    int o = i >> 8, k = i & 255; WaT[o * 256 + k] = f2bf(ldf(Wa, (size_t)k * 256 + o, isf32));
  } else if (i < 98304) {
    int j = i - 65536; int o = j >> 8, k = j & 255;
    WbT[o * 256 + k] = f2bf(ldf(Wb, (size_t)k * 128 + o, isf32));
  } else if (i < 106496) {
    int j = i - 98304; int jj = j >> 7, k = j & 127;
    W1T[jj * 128 + k] = f2bf(ldf(W1, (size_t)k * 128 + jj, isf32));
  } else {
    int j = i - 106496; int jj = j >> 7, k = j & 127;
    W2T[jj * 128 + k] = f2bf(ldf(W2, (size_t)k * 128 + 64 + jj, isf32));
  }
}

// ---------------- fused MLP + first hW ----------------
// hT = tanh(relu([x,hz]@Wa+ba)@Wb+bb)  (transposed store), and
// hW1T[(b*64+j)][n] = sum_d W1T[j][d] * h0[n-row][d]  (epilogue in-LDS GEMM).
// LDS (80KB, 2 blocks/CU):
//   [0,16384)    Afull 8 chunks x [64x32 quad-major]   -> phase2 B tri (3x4096) -> hN
//   [16384,40960) phase1 B tri (3x8192)                -> Z [64][264]
__global__ __launch_bounds__(256, 2) void mlp_fused(const void* __restrict__ x,
                                                    const void* __restrict__ hz,
                                                    const u16* __restrict__ WaT,
                                                    const void* __restrict__ ba,
                                                    const u16* __restrict__ WbT,
                                                    const void* __restrict__ bb,
                                                    const u16* __restrict__ W1T,
                                                    u16* __restrict__ hT,
                                                    u16* __restrict__ hW,
                                                    const u32* __restrict__ flag) {
  __shared__ __align__(16) u16 smem[40960];   // exactly 80 KB
  u16* Afull = smem;
  u16* Zp = smem + 16384;
  u16* hN = smem;
  u32 isf32 = flag[0];
  int tid = threadIdx.x, lane = tid & 63, wave = tid >> 6;
  int col = lane & 15, quad = lane >> 4;
  int r0 = blockIdx.x * 64;
  int b = r0 >> 11;

  auto stageB1 = [&](int buf, int kk) {    // WaT chunk kk: 256 rows x 32k (4 vmem)
    u16* lb = smem + 16384 + buf * 8192;
    stage128x32q(WaT + kk * 32, 256, lb, wave, lane);
    stage128x32q(WaT + (size_t)128 * 256 + kk * 32, 256, lb + 4096, wave, lane);
  };
  auto stageB2 = [&](int buf, int kk) {    // WbT chunk kk: 128 rows x 32k (2 vmem)
    stage128x32q(WbT + kk * 32, 256, smem + buf * 4096, wave, lane);
  };

  f4 acc[4][4] = {};
  auto P1 = [&](int buf, int kk) {
    const u16* lb = smem + 16384 + buf * 8192;
    bf8 af[4], bfr[4];
#pragma unroll
    for (int mi = 0; mi < 4; ++mi)
      af[mi] = *(const bf8*)&Afull[kk * 2048 + mi * 512 + quad * 128 + col * 8];
#pragma unroll
    for (int nj = 0; nj < 4; ++nj)
      bfr[nj] = *(const bf8*)&lb[(wave * 4 + nj) * 512 + quad * 128 + col * 8];
    __builtin_amdgcn_s_setprio(1);
#pragma unroll
    for (int mi = 0; mi < 4; ++mi)
#pragma unroll
      for (int nj = 0; nj < 4; ++nj)
        acc[mi][nj] = __builtin_amdgcn_mfma_f32_16x16x32_bf16(af[mi], bfr[nj], acc[mi][nj], 0, 0, 0);
    __builtin_amdgcn_s_setprio(0);
  };

  // prologue: issue first two B tiles, then preload A (compiler's waits for the
  // A loads drain the stages too -- they are older in the vmcnt FIFO).
  stageB1(0, 0); stageB1(1, 1);
  {
    int r = ((tid >> 6) << 4) | (tid & 15);      // row 0..63
    int c0 = ((tid >> 4) & 3) * 8;               // 0,8,16,24
#pragma unroll
    for (int kk = 0; kk < 8; ++kk) {
      const void* src = (kk < 4) ? x : hz;
      int cc = (kk & 3) * 32 + c0;
      size_t g = (size_t)(r0 + r) * 128 + cc;
      uint4 pk;
      if (isf32) {
        f4 v0 = *(const f4*)&((const float*)src)[g];
        f4 v1 = *(const f4*)&((const float*)src)[g + 4];
        pk.x = (u32)f2bf(v0[0]) | ((u32)f2bf(v0[1]) << 16);
        pk.y = (u32)f2bf(v0[2]) | ((u32)f2bf(v0[3]) << 16);
        pk.z = (u32)f2bf(v1[0]) | ((u32)f2bf(v1[1]) << 16);
        pk.w = (u32)f2bf(v1[2]) | ((u32)f2bf(v1[3]) << 16);
      } else {
        pk = *(const uint4*)&((const u16*)src)[g];
      }
      *(uint4*)&Afull[kk * 2048 + tid * 8] = pk;   // linear: conflict-free
    }
  }
  __syncthreads();   // A + tiles 0,1 landed

  // phase 1: Z = relu(u @ Wa + ba); counted-vmcnt tri-buffer pipeline
#pragma unroll 1
  for (int kk0 = 0; kk0 < 6; kk0 += 3) {
    WAITVM(4); BARS; stageB1(2, kk0 + 2); P1(0, kk0);
    WAITVM(4); BARS; stageB1(0, kk0 + 3); P1(1, kk0 + 1);
    WAITVM(4); BARS; stageB1(1, kk0 + 4); P1(2, kk0 + 2);
  }
  WAITVM(4); BARS; P1(0, 6);
  WAITVM(0); BARS; P1(1, 7);
  __syncthreads();   // everyone done with Afull + B1 buffers

  // prefetch first two WbT tiles (into old Afull region), then write Z
  stageB2(0, 0); stageB2(1, 1);
#pragma unroll
  for (int mi = 0; mi < 4; ++mi)
#pragma unroll
    for (int nj = 0; nj < 4; ++nj) {
      int o = wave * 64 + nj * 16 + col;
      float bav = ldf(ba, o, isf32);
      int rl = mi * 16 + quad * 4;
#pragma unroll
      for (int r = 0; r < 4; ++r)
        Zp[(rl + r) * 264 + o] = f2bf(fmaxf(acc[mi][nj][r] + bav, 0.f));
    }
  asm volatile("s_waitcnt lgkmcnt(0)" ::: "memory");   // Z writes done (vmcnt NOT drained)
  BARS;

  // phase 2: h0 = tanh(Z @ Wb + bb)
  f4 acc2[4][2] = {};
  auto P2 = [&](int buf, int kk) {
    const u16* lb = smem + buf * 4096;
    bf8 az[4], bw[2];
#pragma unroll
    for (int mi = 0; mi < 4; ++mi)
      az[mi] = *(const bf8*)&Zp[(mi * 16 + col) * 264 + kk * 32 + quad * 8];
#pragma unroll
    for (int nj = 0; nj < 2; ++nj)
      bw[nj] = *(const bf8*)&lb[(wave * 2 + nj) * 512 + quad * 128 + col * 8];
    __builtin_amdgcn_s_setprio(1);
#pragma unroll
    for (int mi = 0; mi < 4; ++mi)
#pragma unroll
      for (int nj = 0; nj < 2; ++nj)
        acc2[mi][nj] = __builtin_amdgcn_mfma_f32_16x16x32_bf16(az[mi], bw[nj], acc2[mi][nj], 0, 0, 0);
    __builtin_amdgcn_s_setprio(0);
  };
#pragma unroll 1
  for (int kk0 = 0; kk0 < 6; kk0 += 3) {
    WAITVM(2); BARS; stageB2(2, kk0 + 2); P2(0, kk0);
    WAITVM(2); BARS; stageB2(0, kk0 + 3); P2(1, kk0 + 1);
    WAITVM(2); BARS; stageB2(1, kk0 + 4); P2(2, kk0 + 2);
  }
  WAITVM(2); BARS; P2(0, 6);
  WAITVM(0); BARS; P2(1, 7);
  __syncthreads();   // B2 buffers dead -> hN overlay safe

  // epilogue: tanh(+bb) -> global hT (transposed) AND hN[r][d] staging for hW1
#pragma unroll
  for (int mi = 0; mi < 4; ++mi)
#pragma unroll
    for (int nj = 0; nj < 2; ++nj) {
      int d = wave * 32 + nj * 16 + col;
      float bbv = ldf(bb, d, isf32);
      int rl = mi * 16 + quad * 4;
      int rabs = r0 + rl;
      int n = rabs & 2047;
      u16 p[4];
#pragma unroll
      for (int r = 0; r < 4; ++r) {
        p[r] = f2bf(tanhf(acc2[mi][nj][r] + bbv));
        hN[(rl + r) * 136 + d] = p[r];
      }
      u64 pk = (u64)p[0] | ((u64)p[1] << 16) | ((u64)p[2] << 32) | ((u64)p[3] << 48);
      *(u64*)&hT[(size_t)(b * 128 + d) * 2048 + n] = pk;
    }
  __syncthreads();

  // hW1: out[j][r] = sum_d W1T[j][d] * hN[r][d]; wave covers r in [wave*16, wave*16+16)
  f4 acc3[4] = {};
#pragma unroll
  for (int ks = 0; ks < 4; ++ks) {
    bf8 aw[4], bg;
#pragma unroll
    for (int mi = 0; mi < 4; ++mi)
      aw[mi] = *(const bf8*)&W1T[(size_t)(mi * 16 + col) * 128 + ks * 32 + quad * 8];
    bg = *(const bf8*)&hN[(wave * 16 + col) * 136 + ks * 32 + quad * 8];
#pragma unroll
    for (int mi = 0; mi < 4; ++mi)
      acc3[mi] = __builtin_amdgcn_mfma_f32_16x16x32_bf16(aw[mi], bg, acc3[mi], 0, 0, 0);
  }
#pragma unroll
  for (int mi = 0; mi < 4; ++mi) {
    int rloc = wave * 16 + col;
    int ng = (r0 & 2047) + rloc;
#pragma unroll
    for (int r = 0; r < 4; ++r) {
      int j = mi * 16 + quad * 4 + r;
      hW[(size_t)(b * 64 + j) * 2048 + ng] = f2bf(acc3[mi][r]);
    }
  }
}

// ---------------- fused diffusion step (v4: counted-vmcnt tri-buffer) ----
// Big GEMM: G[m=(b,j)][n2] = sum_n hWT[(b*64+j)][n] * adjb[n2][n]  (64x128 tile, K=2048)
// BK=64, 32 K-tiles, 3 LDS buffers of 24KB; per iter: vmcnt(6) -> barrier ->
// stage tile t+2 -> ds_read + 32 MFMA. Update: nh = hin + DT*tanh(G) (eps step:
// *= clip(eps,0,0.1)); write updated half + copy untouched half. If WnT:
// stage hnew into gN[n][d], produce hWout = WnT @ gN (in-LDS pass-2).
__global__ __launch_bounds__(256, 2) void fused_step2(const u16* __restrict__ hin,
                                                      const u16* __restrict__ hWT,
                                                      const u16* __restrict__ adjb,
                                                      const u16* __restrict__ WnT,
                                                      const void* __restrict__ eps,
                                                      u16* __restrict__ hout,
                                                      u16* __restrict__ hWout,
                                                      int half, const u32* __restrict__ flag) {
  __shared__ __align__(16) u16 smem[36864];   // 72 KB: 3 x (lA 4096 | lB 8192)
  u16* gN = smem;               // [128][136] = 17408 u16, overlays post K-loop
  u32 isf32 = flag[0];
  int tid = threadIdx.x, lane = tid & 63, wave = tid >> 6;
  int col = lane & 15, quad = lane >> 4;
  int b = blockIdx.y;
  int n0 = blockIdx.x * 128;

  const u16* Arow = hWT + (size_t)(b * 64) * 2048;
  const u16* Brow = adjb + (size_t)n0 * 2048;

  auto STAGE = [&](int buf, int t) {   // 6 vmem per wave
    int k0 = t * 64;
    u16* la = smem + buf * 12288;
    u16* lb = la + 4096;
#pragma unroll
    for (int p = 0; p < 2; ++p) {
      stage64x32q(Arow + k0 + p * 32, 2048, la + p * 2048, wave, lane);
      stage128x32q(Brow + k0 + p * 32, 2048, lb + p * 4096, wave, lane);
    }
  };

  f4 acc[4][2] = {};
  auto COMP = [&](int buf) {
    const u16* la = smem + buf * 12288;
    const u16* lb = la + 4096;
    bf8 af[2][4], bfr[2][2];
#pragma unroll
    for (int p = 0; p < 2; ++p) {
#pragma unroll
      for (int mi = 0; mi < 4; ++mi)
        af[p][mi] = *(const bf8*)&la[p * 2048 + mi * 512 + quad * 128 + col * 8];
#pragma unroll
      for (int nj = 0; nj < 2; ++nj)
        bfr[p][nj] = *(const bf8*)&lb[p * 4096 + (wave * 2 + nj) * 512 + quad * 128 + col * 8];
    }
    __builtin_amdgcn_s_setprio(1);
#pragma unroll
    for (int p = 0; p < 2; ++p)
#pragma unroll
      for (int mi = 0; mi < 4; ++mi)
#pragma unroll
        for (int nj = 0; nj < 2; ++nj)
          acc[mi][nj] = __builtin_amdgcn_mfma_f32_16x16x32_bf16(af[p][mi], bfr[p][nj], acc[mi][nj], 0, 0, 0);
    __builtin_amdgcn_s_setprio(0);
  };

  STAGE(0, 0); STAGE(1, 1);
#pragma unroll 1
  for (int kk0 = 0; kk0 < 30; kk0 += 3) {
    WAITVM(6); BARS; STAGE(2, kk0 + 2); COMP(0);
    WAITVM(6); BARS; STAGE(0, kk0 + 3); COMP(1);
    WAITVM(6); BARS; STAGE(1, kk0 + 4); COMP(2);
  }
  WAITVM(6); BARS; COMP(0);   // t=30
  WAITVM(0); BARS; COMP(1);   // t=31
  __syncthreads();            // buffers dead -> gN overlay safe

  bool has_eps = (eps != nullptr);
  bool mk_hw = (WnT != nullptr);
  int dBase = half * 64;
  // update + write updated half; stage nh into gN[n][dBase+j]
#pragma unroll
  for (int mi = 0; mi < 4; ++mi)
#pragma unroll
    for (int nj = 0; nj < 2; ++nj) {
      int j0 = mi * 16 + quad * 4;
      int nl = wave * 32 + nj * 16 + col;
      int n = n0 + nl;
      float ev[4];
      if (has_eps) {
        size_t eoff = ((size_t)b * 2048 + n) * 64 + j0;
        if (isf32) {
          f4 e = *(const f4*)&((const float*)eps)[eoff];
          ev[0] = e[0]; ev[1] = e[1]; ev[2] = e[2]; ev[3] = e[3];
        } else {
          u64 e = *(const u64*)&((const u16*)eps)[eoff];
          ev[0] = bf2f((u16)e); ev[1] = bf2f((u16)(e >> 16));
          ev[2] = bf2f((u16)(e >> 32)); ev[3] = bf2f((u16)(e >> 48));
        }
      }
      u16 pv[4];
#pragma unroll
      for (int r = 0; r < 4; ++r) {
        int j = j0 + r;
        size_t idx = (size_t)(b * 128 + dBase + j) * 2048 + n;
        float hold = bf2f(hin[idx]);
        float nh = hold + 0.01f * tanhf(acc[mi][nj][r]);
        if (has_eps) {
          float e = fminf(fmaxf(ev[r], 0.f), 0.1f);
          nh = e * nh;
        }
        pv[r] = f2bf(nh);
        hout[idx] = pv[r];
      }
      if (mk_hw) {
        u64 pk = (u64)pv[0] | ((u64)pv[1] << 16) | ((u64)pv[2] << 32) | ((u64)pv[3] << 48);
        *(u64*)&gN[nl * 136 + dBase + j0] = pk;
      }
    }

  // copy untouched half to hout; also scatter into gN[n][oh+row]
  {
    int oh = (1 - half) * 64;
    const u16* src = hin + (size_t)(b * 128 + oh) * 2048 + n0;
    u16* dst = hout + (size_t)(b * 128 + oh) * 2048 + n0;
#pragma unroll
    for (int i = 0; i < 4; ++i) {
      int idx = i * 256 + tid;
      int rr = idx >> 4;
      int cc = (idx & 15) * 8;
      uint4 v = *(const uint4*)&src[(size_t)rr * 2048 + cc];
      *(uint4*)&dst[(size_t)rr * 2048 + cc] = v;
      if (mk_hw) {
        u16 t[8];
        *(uint4*)t = v;
#pragma unroll
        for (int q = 0; q < 8; ++q) gN[(cc + q) * 136 + oh + rr] = t[q];
      }
    }
  }

  if (mk_hw) {
    __syncthreads();
    // next hW: out[j'][n] = sum_d WnT[j'][d] * gN[n][d]
    f4 acc2[4][2] = {};
#pragma unroll
    for (int ks = 0; ks < 4; ++ks) {
      bf8 aw[4], bg[2];
#pragma unroll
      for (int mi = 0; mi < 4; ++mi)
        aw[mi] = *(const bf8*)&WnT[(size_t)(mi * 16 + col) * 128 + ks * 32 + quad * 8];
#pragma unroll
      for (int nj = 0; nj < 2; ++nj)
        bg[nj] = *(const bf8*)&gN[(wave * 32 + nj * 16 + col) * 136 + ks * 32 + quad * 8];
#pragma unroll
      for (int mi = 0; mi < 4; ++mi)
#pragma unroll
        for (int nj = 0; nj < 2; ++nj)
          acc2[mi][nj] = __builtin_amdgcn_mfma_f32_16x16x32_bf16(aw[mi], bg[nj], acc2[mi][nj], 0, 0, 0);
    }
#pragma unroll
    for (int mi = 0; mi < 4; ++mi)
#pragma unroll
      for (int nj = 0; nj < 2; ++nj) {
        int jp0 = mi * 16 + quad * 4;
        int n = n0 + wave * 32 + nj * 16 + col;
#pragma unroll
        for (int r = 0; r < 4; ++r)
          hWout[(size_t)(b * 64 + jp0 + r) * 2048 + n] = f2bf(acc2[mi][nj][r]);
      }
  }
}

// ---------------- final un-transpose: out[b][n][d] = hT[(b*128+d)][n] ----------------
__global__ void untranspose(const u16* __restrict__ hT, void* __restrict__ out,
                            const u32* __restrict__ flag) {
  __shared__ __align__(16) u16 t[64][65];
  u32 isf32 = flag[0];
  int b = blockIdx.z, d0 = blockIdx.y * 64, n0 = blockIdx.x * 64;
  int tid = threadIdx.x;
#pragma unroll
  for (int i = 0; i < 16; ++i) {
    int idx = tid + i * 256;
    int r = idx >> 6, c = idx & 63;
    t[r][c] = hT[(size_t)(b * 128 + d0 + r) * 2048 + n0 + c];
  }
  __syncthreads();
#pragma unroll
  for (int i = 0; i < 16; ++i) {
    int idx = tid + i * 256;
    int r = idx >> 6, c = idx & 63;  // r = n-local, c = d-local
    size_t o = (size_t)(b * 2048 + n0 + r) * 128 + d0 + c;
    if (isf32) ((float*)out)[o] = bf2f(t[c][r]);
    else       ((u16*)out)[o] = t[c][r];
  }
}

extern "C" void kernel_launch(void* const* d_in, const int* in_sizes, int n_in,
                              void* d_out, int out_size, void* d_ws, size_t ws_size,
                              hipStream_t stream) {
  const void* x   = d_in[0];
  const void* hz  = d_in[1];
  const void* adj = d_in[2];
  const void* W1  = d_in[3];
  const void* W2  = d_in[4];
  const void* Wa  = d_in[5];
  const void* ba  = d_in[6];
  const void* Wb  = d_in[7];
  const void* bb  = d_in[8];
  const void* eps = d_in[9];

  // workspace layout (44.3 MB):
  //   hA   @  0M   16.78 MB  transposed h ping buffer (bf16 [4096][2048])
  //   adjb @ 17M    8.39 MB  adj bf16 [2048][2048]
  //   hWa  @ 26M    8.39 MB  hW ping (bf16 [2048][2048])
  //   hWb  @ 35M    8.39 MB  hW pong
  //   weights @ 44M (229 KB), flag after
  // hB (pong h) = d_out scratch; untranspose fully rewrites d_out at the end.
  char* ws = (char*)d_ws;
  u16* hA   = (u16*)(ws);
  u16* adjb = (u16*)(ws + (17ull << 20));
  u16* hWa  = (u16*)(ws + (26ull << 20));
  u16* hWb  = (u16*)(ws + (35ull << 20));
  u16* WaT  = (u16*)(ws + (44ull << 20));
  u16* WbT  = WaT + 256 * 256;
  u16* W1T  = WbT + 128 * 256;
  u16* W2T  = W1T + 64 * 128;
  u32* flag = (u32*)(W2T + 64 * 128);
  u16* hB   = (u16*)d_out;

  detect_dtype<<<dim3(1), dim3(256), 0, stream>>>((const u16*)x, flag);
  prep_weights<<<dim3(448), dim3(256), 0, stream>>>(Wa, Wb, W1, W2, WaT, WbT, W1T, W2T, flag);
  cvt_bf16<<<dim3(4096), dim3(256), 0, stream>>>(adj, adjb, 0, 4194304, flag);
  mlp_fused<<<dim3(1024), dim3(256), 0, stream>>>(x, hz, WaT, ba, WbT, bb, W1T, hA, hWa, flag);
  // step 1 (half=0, consumes hWa=h0@W1h, produces hWb=h1@W2h)
  fused_step2<<<dim3(16, 32), dim3(256), 0, stream>>>(hA, hWa, adjb, W2T, nullptr, hB, hWb, 0, flag);
  // step 2 (half=1, eps; consumes hWb, produces hWa=h2@W1h)
  fused_step2<<<dim3(16, 32), dim3(256), 0, stream>>>(hB, hWb, adjb, W1T, eps, hA, hWa, 1, flag);
  // step 3 (half=0; consumes hWa, produces hWb=h3@W2h)
  fused_step2<<<dim3(16, 32), dim3(256), 0, stream>>>(hA, hWa, adjb, W2T, nullptr, hB, hWb, 0, flag);
  // step 4 (half=1, eps; consumes hWb, no next hW)
  fused_step2<<<dim3(16, 32), dim3(256), 0, stream>>>(hB, hWb, adjb, nullptr, eps, hA, nullptr, 1, flag);
  untranspose<<<dim3(32, 2, 32), dim3(256), 0, stream>>>(hA, d_out, flag);
}